// Round 11
// baseline (200.189 us; speedup 1.0000x reference)
//
#include <hip/hip_runtime.h>
#include <hip/hip_bf16.h>

typedef unsigned int uint;
typedef unsigned short ushort;
typedef __attribute__((ext_vector_type(8))) short bf16x8;
typedef __attribute__((ext_vector_type(4))) float f32x4;

static __device__ __forceinline__ ushort f2b(float f) {
  __hip_bfloat16 h = __float2bfloat16(f);  // RNE
  union { __hip_bfloat16 h; ushort u; } cv; cv.h = h; return cv.u;
}
static __device__ __forceinline__ float blo(uint u) { return __uint_as_float(u << 16); }
static __device__ __forceinline__ float bhi(uint u) { return __uint_as_float(u & 0xffff0000u); }

#define BUCK_SHIFT 7
#define BUCK_SIZE 128
#define NBUCK_MAX 1024
#define CHUNK 4096
#define CAP_SHIFT 12   // 4096 slots per bucket (avg fill 2048; >20 sigma slack)
#define LDK 136        // padded LDS k-stride (shorts)

// ---------------- bucket init ----------------

__global__ void binit(int* __restrict__ bcur, int nbuck) {
  int b = blockIdx.x * blockDim.x + threadIdx.x;
  if (b < nbuck) bcur[b] = b << CAP_SHIFT;
}

// ---------------- single-pass bucketed partition (int4 edge reads) ----------------
// pairs record: src | (dst & 127) << 24   (src < 2^24)

__launch_bounds__(256)
__global__ void bucket_scatter(const int* __restrict__ src, const int* __restrict__ dst,
                               int* __restrict__ bcur, uint* __restrict__ pairs,
                               int E, int nbuck) {
  __shared__ int hist[NBUCK_MAX];
  __shared__ int base[NBUCK_MAX];
  int t = threadIdx.x;
  int e0 = blockIdx.x * CHUNK, e1 = min(e0 + CHUNK, E);
  int nv = (e1 - e0) >> 2;  // int4 groups in this chunk (CHUNK and E are %4==0)
  const int4* dst4 = (const int4*)(dst + e0);
  const int4* src4 = (const int4*)(src + e0);
  for (int i = t; i < nbuck; i += 256) hist[i] = 0;
  __syncthreads();
  for (int i = t; i < nv; i += 256) {
    int4 d = dst4[i];
    atomicAdd(&hist[d.x >> BUCK_SHIFT], 1);
    atomicAdd(&hist[d.y >> BUCK_SHIFT], 1);
    atomicAdd(&hist[d.z >> BUCK_SHIFT], 1);
    atomicAdd(&hist[d.w >> BUCK_SHIFT], 1);
  }
  __syncthreads();
  for (int i = t; i < nbuck; i += 256) {
    int h = hist[i];
    base[i] = h ? atomicAdd(&bcur[i], h) : 0;
    hist[i] = 0;
  }
  __syncthreads();
  for (int i = t; i < nv; i += 256) {
    int4 d = dst4[i];
    int4 s = src4[i];
#pragma unroll
    for (int k = 0; k < 4; ++k) {
      int dd = (k == 0) ? d.x : (k == 1) ? d.y : (k == 2) ? d.z : d.w;
      int ss = (k == 0) ? s.x : (k == 1) ? s.y : (k == 2) ? s.z : s.w;
      int b = dd >> BUCK_SHIFT;
      int pos = base[b] + atomicAdd(&hist[b], 1);
      if (pos < ((b + 1) << CAP_SHIFT))  // capacity guard
        pairs[pos] = (uint)ss | ((uint)(dd & (BUCK_SIZE - 1)) << 24);
    }
  }
}

// ---------------- per-bucket node grouping + (beg,end) + dinv ----------------

__launch_bounds__(128)
__global__ void fine_fill2(const int* __restrict__ bcur, const uint* __restrict__ pairs,
                           int* __restrict__ esrc, int2* __restrict__ rp,
                           float* __restrict__ dinv, int n, int nbuck) {
  __shared__ int lhist[BUCK_SIZE];
  __shared__ int lcur[BUCK_SIZE];
  int buck = blockIdx.x;
  int nlo = buck << BUCK_SHIFT;
  int cnt = min(BUCK_SIZE, n - nlo);
  int t = threadIdx.x;  // 128 threads
  lhist[t] = 0;
  __syncthreads();
  int beg = buck << CAP_SHIFT;
  int end = min(bcur[buck], (buck + 1) << CAP_SHIFT);
  for (int j = beg + t; j < end; j += 128)
    atomicAdd(&lhist[pairs[j] >> 24], 1);
  __syncthreads();
  int deg = lhist[t];
  for (int off = 1; off < 128; off <<= 1) {
    int y = (t >= off) ? lhist[t - off] : 0;
    __syncthreads();
    lhist[t] += y;
    __syncthreads();
  }
  int excl = lhist[t] - deg;
  if (t < cnt) {
    rp[nlo + t] = make_int2(beg + excl, beg + excl + deg);
    dinv[nlo + t] = rsqrtf((float)(deg + 1));  // +1 self-loop
    lcur[t] = beg + excl;
  }
  __syncthreads();
  for (int j = beg + t; j < end; j += 128) {
    uint p = pairs[j];
    int pos = atomicAdd(&lcur[p >> 24], 1);
    esrc[pos] = (int)(p & 0xFFFFFFu);
  }
}

// ---------------- weight transpose prep ----------------

__global__ void prep_wt(const float* __restrict__ W1, const float* __restrict__ W2,
                        ushort* __restrict__ WT1, ushort* __restrict__ WT2) {
  int i = blockIdx.x * 256 + threadIdx.x;
  if (i < 128 * 128) {
    int nn = i >> 7, k = i & 127;
    WT1[nn * 128 + k] = f2b(W1[k * 128 + nn]);
  }
  if (i < 48 * 128) {
    int nn = i >> 7, k = i & 127;
    WT2[nn * 128 + k] = (nn < 40) ? f2b(W2[k * 40 + nn]) : (ushort)0;
  }
}

// ---------------- GEMM1 (MFMA): h1s = bf16( (X@W1) * dinv[row] ) ----------------

__launch_bounds__(256)
__global__ void gemm1_mfma(const float* __restrict__ X, const ushort* __restrict__ WT,
                           const float* __restrict__ dinv, ushort* __restrict__ H1S, int n) {
  __shared__ ushort sA[128 * LDK];
  __shared__ ushort sB[128 * LDK];
  int tid = threadIdx.x;
  int row0 = blockIdx.x * 128;
  for (int i = tid; i < 128 * 32; i += 256) {
    int r = i >> 5, c4 = (i & 31) * 4;
    int row = row0 + r;
    float4 v = (row < n) ? *(const float4*)(X + (size_t)row * 128 + c4)
                         : make_float4(0.f, 0.f, 0.f, 0.f);
    uint2 w;
    w.x = (uint)f2b(v.x) | ((uint)f2b(v.y) << 16);
    w.y = (uint)f2b(v.z) | ((uint)f2b(v.w) << 16);
    *(uint2*)(sA + r * LDK + c4) = w;
  }
  for (int i = tid; i < 128 * 16; i += 256) {
    int r = i >> 4, c8 = (i & 15) * 8;
    *(uint4*)(sB + r * LDK + c8) = *(const uint4*)(WT + r * 128 + c8);
  }
  __syncthreads();
  int wv = tid >> 6, lane = tid & 63;
  int lr = lane & 15, lg = lane >> 4;
  f32x4 acc[2][8] = {};
  const ushort* aBase = sA + (wv * 32 + lr) * LDK + lg * 8;
  const ushort* bBase = sB + lr * LDK + lg * 8;
#pragma unroll
  for (int k0 = 0; k0 < 128; k0 += 32) {
    bf16x8 a0 = *(const bf16x8*)(aBase + k0);
    bf16x8 a1 = *(const bf16x8*)(aBase + 16 * LDK + k0);
#pragma unroll
    for (int ct = 0; ct < 8; ++ct) {
      bf16x8 b = *(const bf16x8*)(bBase + ct * 16 * LDK + k0);
      acc[0][ct] = __builtin_amdgcn_mfma_f32_16x16x32_bf16(a0, b, acc[0][ct], 0, 0, 0);
      acc[1][ct] = __builtin_amdgcn_mfma_f32_16x16x32_bf16(a1, b, acc[1][ct], 0, 0, 0);
    }
  }
#pragma unroll
  for (int rt = 0; rt < 2; ++rt) {
#pragma unroll
    for (int rr = 0; rr < 4; ++rr) {
      int row = row0 + wv * 32 + rt * 16 + lg * 4 + rr;
      if (row < n) {
        float dv = dinv[row];
        ushort* o = H1S + (size_t)row * 128 + lr;
#pragma unroll
        for (int ct = 0; ct < 8; ++ct)
          o[ct * 16] = f2b(acc[rt][ct][rr] * dv);
      }
    }
  }
}

// ---------------- GEMM2 (MFMA): h2s (stride 64) = bf16( (Hidden_f32@W2) * dinv[row] ) ----------------

__launch_bounds__(256)
__global__ void gemm2_mfma(const float* __restrict__ Hf, const ushort* __restrict__ WT2,
                           const float* __restrict__ dinv, ushort* __restrict__ H2S, int n) {
  __shared__ ushort sA[128 * LDK];
  __shared__ ushort sB[48 * LDK];
  int tid = threadIdx.x;
  int row0 = blockIdx.x * 128;
  for (int i = tid; i < 128 * 32; i += 256) {
    int r = i >> 5, c4 = (i & 31) * 4;
    int row = row0 + r;
    float4 v = (row < n) ? *(const float4*)(Hf + (size_t)row * 128 + c4)
                         : make_float4(0.f, 0.f, 0.f, 0.f);
    uint2 w;
    w.x = (uint)f2b(v.x) | ((uint)f2b(v.y) << 16);
    w.y = (uint)f2b(v.z) | ((uint)f2b(v.w) << 16);
    *(uint2*)(sA + r * LDK + c4) = w;
  }
  for (int i = tid; i < 48 * 16; i += 256) {
    int r = i >> 4, c8 = (i & 15) * 8;
    *(uint4*)(sB + r * LDK + c8) = *(const uint4*)(WT2 + r * 128 + c8);
  }
  __syncthreads();
  int wv = tid >> 6, lane = tid & 63;
  int lr = lane & 15, lg = lane >> 4;
  f32x4 acc[2][3] = {};
  const ushort* aBase = sA + (wv * 32 + lr) * LDK + lg * 8;
  const ushort* bBase = sB + lr * LDK + lg * 8;
#pragma unroll
  for (int k0 = 0; k0 < 128; k0 += 32) {
    bf16x8 a0 = *(const bf16x8*)(aBase + k0);
    bf16x8 a1 = *(const bf16x8*)(aBase + 16 * LDK + k0);
#pragma unroll
    for (int ct = 0; ct < 3; ++ct) {
      bf16x8 b = *(const bf16x8*)(bBase + ct * 16 * LDK + k0);
      acc[0][ct] = __builtin_amdgcn_mfma_f32_16x16x32_bf16(a0, b, acc[0][ct], 0, 0, 0);
      acc[1][ct] = __builtin_amdgcn_mfma_f32_16x16x32_bf16(a1, b, acc[1][ct], 0, 0, 0);
    }
  }
#pragma unroll
  for (int rt = 0; rt < 2; ++rt) {
#pragma unroll
    for (int rr = 0; rr < 4; ++rr) {
      int row = row0 + wv * 32 + rt * 16 + lg * 4 + rr;
      if (row < n) {
        float dv = dinv[row];
#pragma unroll
        for (int ct = 0; ct < 3; ++ct) {
          int col = ct * 16 + lr;
          if (col < 40)
            H2S[(size_t)row * 64 + col] = f2b(acc[rt][ct][rr] * dv);
        }
      }
    }
  }
}

// ---------------- gather 128-wide: 8 loads in flight, 32-bit offsets ----------------

__launch_bounds__(256)
__global__ void gather128(const int2* __restrict__ rp, const int* __restrict__ esrc,
                          const float* __restrict__ dinv, const uint* __restrict__ H,
                          const float* __restrict__ b, float* __restrict__ out, int n) {
  int lane = threadIdx.x & 63;
  int node = blockIdx.x * 4 + (threadIdx.x >> 6);
  if (node >= n) return;
  uint lane4 = (uint)lane << 2;
  const char* Hc = (const char*)H;
  int2 be = rp[node];
  int j = be.x, end = be.y;
  float ax[8] = {}, ay[8] = {};
  for (; j + 8 <= end; j += 8) {
    uint u[8];
#pragma unroll
    for (int k = 0; k < 8; ++k)
      u[k] = *(const uint*)(Hc + (((uint)esrc[j + k] << 8) + lane4));
#pragma unroll
    for (int k = 0; k < 8; ++k) { ax[k] += blo(u[k]); ay[k] += bhi(u[k]); }
  }
  if (j + 4 <= end) {
    uint u[4];
#pragma unroll
    for (int k = 0; k < 4; ++k)
      u[k] = *(const uint*)(Hc + (((uint)esrc[j + k] << 8) + lane4));
#pragma unroll
    for (int k = 0; k < 4; ++k) { ax[k] += blo(u[k]); ay[k] += bhi(u[k]); }
    j += 4;
  }
  int rem = end - j;  // 0..3
  if (rem) {
    uint u[3];
    bool p[3];
#pragma unroll
    for (int k = 0; k < 3; ++k) {
      p[k] = k < rem;
      int s = p[k] ? esrc[j + k] : node;
      u[k] = *(const uint*)(Hc + (((uint)s << 8) + lane4));
    }
#pragma unroll
    for (int k = 0; k < 3; ++k) {
      ax[k] += p[k] ? blo(u[k]) : 0.f;
      ay[k] += p[k] ? bhi(u[k]) : 0.f;
    }
  }
  uint us = *(const uint*)(Hc + (((uint)node << 8) + lane4));
  float gx = ((ax[0] + ax[1]) + (ax[2] + ax[3])) + ((ax[4] + ax[5]) + (ax[6] + ax[7]));
  float gy = ((ay[0] + ay[1]) + (ay[2] + ay[3])) + ((ay[4] + ay[5]) + (ay[6] + ay[7]));
  float dd = dinv[node];
  float2 bb = ((const float2*)b)[lane];
  float ox = fmaxf((gx + blo(us)) * dd + bb.x, 0.f);
  float oy = fmaxf((gy + bhi(us)) * dd + bb.y, 0.f);
  float2 o = {ox, oy};
  ((float2*)out)[(size_t)node * 64 + lane] = o;
}

// ---------------- gather 40-wide (128B padded rows): 12 edges in flight ----------------

__launch_bounds__(256)
__global__ void gather40(const int2* __restrict__ rp, const int* __restrict__ esrc,
                         const float* __restrict__ dinv, const uint* __restrict__ H2,
                         const float* __restrict__ b, float* __restrict__ out, int n) {
  int lane = threadIdx.x & 63;
  int node = blockIdx.x * 4 + (threadIdx.x >> 6);
  if (node >= n) return;
  int es = lane / 20;       // 0..2 active, 3 idle
  int c = lane % 20;
  uint c4 = (uint)c << 2;
  bool act = lane < 60;
  const char* Hc = (const char*)H2;
  int2 be = rp[node];
  int j = be.x, end = be.y;
  float ax[4] = {}, ay[4] = {};
  for (; j + 12 <= end; j += 12) {
    uint u[4];
#pragma unroll
    for (int k = 0; k < 4; ++k) {
      int s = act ? esrc[j + 3 * k + es] : node;
      u[k] = *(const uint*)(Hc + (((uint)s << 7) + c4));
    }
    if (act) {
#pragma unroll
      for (int k = 0; k < 4; ++k) { ax[k] += blo(u[k]); ay[k] += bhi(u[k]); }
    }
  }
  if (j + 6 <= end) {
    uint u[2];
#pragma unroll
    for (int k = 0; k < 2; ++k) {
      int s = act ? esrc[j + 3 * k + es] : node;
      u[k] = *(const uint*)(Hc + (((uint)s << 7) + c4));
    }
    if (act) {
#pragma unroll
      for (int k = 0; k < 2; ++k) { ax[k] += blo(u[k]); ay[k] += bhi(u[k]); }
    }
    j += 6;
  }
  int rem = end - j;  // 0..5
  {
    bool pa = act && (es < rem);
    bool pb = act && (3 + es < rem);
    int sa = pa ? esrc[j + es] : node;
    int sb = pb ? esrc[j + 3 + es] : node;
    uint ua = *(const uint*)(Hc + (((uint)sa << 7) + c4));
    uint ub = *(const uint*)(Hc + (((uint)sb << 7) + c4));
    ax[0] += pa ? blo(ua) : 0.f; ay[0] += pa ? bhi(ua) : 0.f;
    ax[1] += pb ? blo(ub) : 0.f; ay[1] += pb ? bhi(ub) : 0.f;
  }
  float gx = (ax[0] + ax[1]) + (ax[2] + ax[3]);
  float gy = (ay[0] + ay[1]) + (ay[2] + ay[3]);
  float tx = gx + __shfl(gx, c + 20) + __shfl(gx, c + 40);
  float ty = gy + __shfl(gy, c + 20) + __shfl(gy, c + 40);
  if (lane < 20) {
    uint us = *(const uint*)(Hc + (((uint)node << 7) + c4));
    float dd = dinv[node];
    float2 bb = ((const float2*)b)[c];
    float2 o = {(tx + blo(us)) * dd + bb.x, (ty + bhi(us)) * dd + bb.y};
    ((float2*)out)[(size_t)node * 20 + c] = o;
  }
}

// ---------------- launch ----------------

extern "C" void kernel_launch(void* const* d_in, const int* in_sizes, int n_in,
                              void* d_out, int out_size, void* d_ws, size_t ws_size,
                              hipStream_t stream) {
  const float* x  = (const float*)d_in[0];
  const int*   ei = (const int*)d_in[1];
  const float* W1 = (const float*)d_in[2];
  const float* b1 = (const float*)d_in[3];
  const float* W2 = (const float*)d_in[4];
  const float* b2 = (const float*)d_in[5];

  int n = in_sizes[0] / 128;   // 100000
  int E = in_sizes[1] / 2;     // 1600000
  const int* src = ei;
  const int* dst = ei + E;

  float* out = (float*)d_out;
  float* logits = out;                    // n*40
  float* hidden = out + (size_t)n * 40;   // n*128

  int nbuck = (n + BUCK_SIZE - 1) >> BUCK_SHIFT;  // 782
  int nchunk = (E + CHUNK - 1) / CHUNK;           // 391
  int ngrow = (n + 127) / 128;                    // 782

  // workspace layout (4-byte units)
  const int PAD = 131072;
  float*  dinv = (float*)d_ws;                          // n
  int2*   rp   = (int2*)((int*)d_ws + PAD);             // n int2 (2*PAD ints)
  int*    bcur = (int*)d_ws + 3 * PAD;                  // 1024
  int*    esrc = (int*)d_ws + 3 * PAD + 1024;           // nbuck<<CAP_SHIFT
  ushort* h1s  = (ushort*)(esrc + ((size_t)nbuck << CAP_SHIFT));  // n*128 bf16
  ushort* h2s  = h1s;                                   // alias h1s (dead after gather128)
  ushort* wt1  = h1s + (size_t)n * 128;                 // 128*128 bf16
  ushort* wt2  = wt1 + 128 * 128;                       // 48*128 bf16
  uint*   pairs = (uint*)h1s;  // aliases h1s: dead before gemm1 writes h1s

  // ---- CSR build (rp, esrc, dinv) + weight prep ----
  binit<<<(nbuck + 255) / 256, 256, 0, stream>>>(bcur, nbuck);
  prep_wt<<<64, 256, 0, stream>>>(W1, W2, wt1, wt2);
  bucket_scatter<<<nchunk, 256, 0, stream>>>(src, dst, bcur, pairs, E, nbuck);
  fine_fill2<<<nbuck, 128, 0, stream>>>(bcur, pairs, esrc, rp, dinv, n, nbuck);

  // ---- layer 1 ----
  gemm1_mfma<<<ngrow, 256, 0, stream>>>(x, wt1, dinv, h1s, n);
  gather128<<<(n + 3) / 4, 256, 0, stream>>>(rp, esrc, dinv, (const uint*)h1s, b1,
                                             hidden, n);

  // ---- layer 2 ----
  gemm2_mfma<<<ngrow, 256, 0, stream>>>(hidden, wt2, dinv, h2s, n);
  gather40<<<(n + 3) / 4, 256, 0, stream>>>(rp, esrc, dinv, (const uint*)h2s, b2,
                                            logits, n);
}

// Round 12
// 197.248 us; speedup vs baseline: 1.0149x; 1.0149x over previous
//
#include <hip/hip_runtime.h>
#include <hip/hip_bf16.h>

typedef unsigned int uint;
typedef unsigned short ushort;
typedef __attribute__((ext_vector_type(8))) short bf16x8;
typedef __attribute__((ext_vector_type(4))) float f32x4;

static __device__ __forceinline__ ushort f2b(float f) {
  __hip_bfloat16 h = __float2bfloat16(f);  // RNE
  union { __hip_bfloat16 h; ushort u; } cv; cv.h = h; return cv.u;
}
static __device__ __forceinline__ float blo(uint u) { return __uint_as_float(u << 16); }
static __device__ __forceinline__ float bhi(uint u) { return __uint_as_float(u & 0xffff0000u); }

#define BUCK_SHIFT 7
#define BUCK_SIZE 128
#define NBUCK_MAX 1024
#define CHUNK 4096
#define CAP_SHIFT 12   // 4096 slots per bucket (avg fill 2048; >20 sigma slack)
#define LDK 136        // padded LDS k-stride (shorts)

// ---------------- bucket init ----------------

__global__ void binit(int* __restrict__ bcur, int nbuck) {
  int b = blockIdx.x * blockDim.x + threadIdx.x;
  if (b < nbuck) bcur[b] = b << CAP_SHIFT;
}

// ---------------- single-pass bucketed partition (int4 edge reads) ----------------
// pairs record: src | (dst & 127) << 24   (src < 2^24)

__launch_bounds__(256)
__global__ void bucket_scatter(const int* __restrict__ src, const int* __restrict__ dst,
                               int* __restrict__ bcur, uint* __restrict__ pairs,
                               int E, int nbuck) {
  __shared__ int hist[NBUCK_MAX];
  __shared__ int base[NBUCK_MAX];
  int t = threadIdx.x;
  int e0 = blockIdx.x * CHUNK, e1 = min(e0 + CHUNK, E);
  int nv = (e1 - e0) >> 2;  // int4 groups in this chunk (CHUNK and E are %4==0)
  const int4* dst4 = (const int4*)(dst + e0);
  const int4* src4 = (const int4*)(src + e0);
  for (int i = t; i < nbuck; i += 256) hist[i] = 0;
  __syncthreads();
  for (int i = t; i < nv; i += 256) {
    int4 d = dst4[i];
    atomicAdd(&hist[d.x >> BUCK_SHIFT], 1);
    atomicAdd(&hist[d.y >> BUCK_SHIFT], 1);
    atomicAdd(&hist[d.z >> BUCK_SHIFT], 1);
    atomicAdd(&hist[d.w >> BUCK_SHIFT], 1);
  }
  __syncthreads();
  for (int i = t; i < nbuck; i += 256) {
    int h = hist[i];
    base[i] = h ? atomicAdd(&bcur[i], h) : 0;
    hist[i] = 0;
  }
  __syncthreads();
  for (int i = t; i < nv; i += 256) {
    int4 d = dst4[i];
    int4 s = src4[i];
#pragma unroll
    for (int k = 0; k < 4; ++k) {
      int dd = (k == 0) ? d.x : (k == 1) ? d.y : (k == 2) ? d.z : d.w;
      int ss = (k == 0) ? s.x : (k == 1) ? s.y : (k == 2) ? s.z : s.w;
      int b = dd >> BUCK_SHIFT;
      int pos = base[b] + atomicAdd(&hist[b], 1);
      if (pos < ((b + 1) << CAP_SHIFT))  // capacity guard
        pairs[pos] = (uint)ss | ((uint)(dd & (BUCK_SIZE - 1)) << 24);
    }
  }
}

// ---------------- per-bucket node grouping + (beg,end) + dinv ----------------

__launch_bounds__(128)
__global__ void fine_fill2(const int* __restrict__ bcur, const uint* __restrict__ pairs,
                           int* __restrict__ esrc, int2* __restrict__ rp,
                           float* __restrict__ dinv, int n, int nbuck) {
  __shared__ int lhist[BUCK_SIZE];
  __shared__ int lcur[BUCK_SIZE];
  int buck = blockIdx.x;
  int nlo = buck << BUCK_SHIFT;
  int cnt = min(BUCK_SIZE, n - nlo);
  int t = threadIdx.x;  // 128 threads
  lhist[t] = 0;
  __syncthreads();
  int beg = buck << CAP_SHIFT;
  int end = min(bcur[buck], (buck + 1) << CAP_SHIFT);
  for (int j = beg + t; j < end; j += 128)
    atomicAdd(&lhist[pairs[j] >> 24], 1);
  __syncthreads();
  int deg = lhist[t];
  for (int off = 1; off < 128; off <<= 1) {
    int y = (t >= off) ? lhist[t - off] : 0;
    __syncthreads();
    lhist[t] += y;
    __syncthreads();
  }
  int excl = lhist[t] - deg;
  if (t < cnt) {
    rp[nlo + t] = make_int2(beg + excl, beg + excl + deg);
    dinv[nlo + t] = rsqrtf((float)(deg + 1));  // +1 self-loop
    lcur[t] = beg + excl;
  }
  __syncthreads();
  for (int j = beg + t; j < end; j += 128) {
    uint p = pairs[j];
    int pos = atomicAdd(&lcur[p >> 24], 1);
    esrc[pos] = (int)(p & 0xFFFFFFu);
  }
}

// ---------------- weight transpose prep ----------------

__global__ void prep_wt(const float* __restrict__ W1, const float* __restrict__ W2,
                        ushort* __restrict__ WT1, ushort* __restrict__ WT2) {
  int i = blockIdx.x * 256 + threadIdx.x;
  if (i < 128 * 128) {
    int nn = i >> 7, k = i & 127;
    WT1[nn * 128 + k] = f2b(W1[k * 128 + nn]);
  }
  if (i < 48 * 128) {
    int nn = i >> 7, k = i & 127;
    WT2[nn * 128 + k] = (nn < 40) ? f2b(W2[k * 40 + nn]) : (ushort)0;
  }
}

// ---------------- GEMM1 (MFMA): h1s = bf16( (X@W1) * dinv[row] ) ----------------

__launch_bounds__(256)
__global__ void gemm1_mfma(const float* __restrict__ X, const ushort* __restrict__ WT,
                           const float* __restrict__ dinv, ushort* __restrict__ H1S, int n) {
  __shared__ ushort sA[128 * LDK];
  __shared__ ushort sB[128 * LDK];
  int tid = threadIdx.x;
  int row0 = blockIdx.x * 128;
  for (int i = tid; i < 128 * 32; i += 256) {
    int r = i >> 5, c4 = (i & 31) * 4;
    int row = row0 + r;
    float4 v = (row < n) ? *(const float4*)(X + (size_t)row * 128 + c4)
                         : make_float4(0.f, 0.f, 0.f, 0.f);
    uint2 w;
    w.x = (uint)f2b(v.x) | ((uint)f2b(v.y) << 16);
    w.y = (uint)f2b(v.z) | ((uint)f2b(v.w) << 16);
    *(uint2*)(sA + r * LDK + c4) = w;
  }
  for (int i = tid; i < 128 * 16; i += 256) {
    int r = i >> 4, c8 = (i & 15) * 8;
    *(uint4*)(sB + r * LDK + c8) = *(const uint4*)(WT + r * 128 + c8);
  }
  __syncthreads();
  int wv = tid >> 6, lane = tid & 63;
  int lr = lane & 15, lg = lane >> 4;
  f32x4 acc[2][8] = {};
  const ushort* aBase = sA + (wv * 32 + lr) * LDK + lg * 8;
  const ushort* bBase = sB + lr * LDK + lg * 8;
#pragma unroll
  for (int k0 = 0; k0 < 128; k0 += 32) {
    bf16x8 a0 = *(const bf16x8*)(aBase + k0);
    bf16x8 a1 = *(const bf16x8*)(aBase + 16 * LDK + k0);
#pragma unroll
    for (int ct = 0; ct < 8; ++ct) {
      bf16x8 b = *(const bf16x8*)(bBase + ct * 16 * LDK + k0);
      acc[0][ct] = __builtin_amdgcn_mfma_f32_16x16x32_bf16(a0, b, acc[0][ct], 0, 0, 0);
      acc[1][ct] = __builtin_amdgcn_mfma_f32_16x16x32_bf16(a1, b, acc[1][ct], 0, 0, 0);
    }
  }
#pragma unroll
  for (int rt = 0; rt < 2; ++rt) {
#pragma unroll
    for (int rr = 0; rr < 4; ++rr) {
      int row = row0 + wv * 32 + rt * 16 + lg * 4 + rr;
      if (row < n) {
        float dv = dinv[row];
        ushort* o = H1S + (size_t)row * 128 + lr;
#pragma unroll
        for (int ct = 0; ct < 8; ++ct)
          o[ct * 16] = f2b(acc[rt][ct][rr] * dv);
      }
    }
  }
}

// ---------------- GEMM2 (MFMA): h2s (stride 64) = bf16( (Hidden_f32@W2) * dinv[row] ) ----------------

__launch_bounds__(256)
__global__ void gemm2_mfma(const float* __restrict__ Hf, const ushort* __restrict__ WT2,
                           const float* __restrict__ dinv, ushort* __restrict__ H2S, int n) {
  __shared__ ushort sA[128 * LDK];
  __shared__ ushort sB[48 * LDK];
  int tid = threadIdx.x;
  int row0 = blockIdx.x * 128;
  for (int i = tid; i < 128 * 32; i += 256) {
    int r = i >> 5, c4 = (i & 31) * 4;
    int row = row0 + r;
    float4 v = (row < n) ? *(const float4*)(Hf + (size_t)row * 128 + c4)
                         : make_float4(0.f, 0.f, 0.f, 0.f);
    uint2 w;
    w.x = (uint)f2b(v.x) | ((uint)f2b(v.y) << 16);
    w.y = (uint)f2b(v.z) | ((uint)f2b(v.w) << 16);
    *(uint2*)(sA + r * LDK + c4) = w;
  }
  for (int i = tid; i < 48 * 16; i += 256) {
    int r = i >> 4, c8 = (i & 15) * 8;
    *(uint4*)(sB + r * LDK + c8) = *(const uint4*)(WT2 + r * 128 + c8);
  }
  __syncthreads();
  int wv = tid >> 6, lane = tid & 63;
  int lr = lane & 15, lg = lane >> 4;
  f32x4 acc[2][3] = {};
  const ushort* aBase = sA + (wv * 32 + lr) * LDK + lg * 8;
  const ushort* bBase = sB + lr * LDK + lg * 8;
#pragma unroll
  for (int k0 = 0; k0 < 128; k0 += 32) {
    bf16x8 a0 = *(const bf16x8*)(aBase + k0);
    bf16x8 a1 = *(const bf16x8*)(aBase + 16 * LDK + k0);
#pragma unroll
    for (int ct = 0; ct < 3; ++ct) {
      bf16x8 b = *(const bf16x8*)(bBase + ct * 16 * LDK + k0);
      acc[0][ct] = __builtin_amdgcn_mfma_f32_16x16x32_bf16(a0, b, acc[0][ct], 0, 0, 0);
      acc[1][ct] = __builtin_amdgcn_mfma_f32_16x16x32_bf16(a1, b, acc[1][ct], 0, 0, 0);
    }
  }
#pragma unroll
  for (int rt = 0; rt < 2; ++rt) {
#pragma unroll
    for (int rr = 0; rr < 4; ++rr) {
      int row = row0 + wv * 32 + rt * 16 + lg * 4 + rr;
      if (row < n) {
        float dv = dinv[row];
#pragma unroll
        for (int ct = 0; ct < 3; ++ct) {
          int col = ct * 16 + lr;
          if (col < 40)
            H2S[(size_t)row * 64 + col] = f2b(acc[rt][ct][rr] * dv);
        }
      }
    }
  }
}

// ---------------- gather 128-wide: quarter-wave rows (4 rows/instr), 16 rows in flight ----------------

__launch_bounds__(256)
__global__ void gather128(const int2* __restrict__ rp, const int* __restrict__ esrc,
                          const float* __restrict__ dinv, const uint* __restrict__ H,
                          const float* __restrict__ b, float* __restrict__ out, int n) {
  int lane = threadIdx.x & 63;
  int node = blockIdx.x * 4 + (threadIdx.x >> 6);
  if (node >= n) return;
  int q = lane >> 4;          // quarter 0..3 = edge slot
  int l = lane & 15;          // covers bf16 cols [8l..8l+7] (16B of the 256B row)
  uint off16 = (uint)l << 4;  // byte offset within row
  const char* Hc = (const char*)H;
  int2 be = rp[node];
  int j = be.x, end = be.y;
  float acc[8] = {};
  // main: 16 edges per iteration, 4 dwordx4 loads in flight (16 rows)
  for (; j + 16 <= end; j += 16) {
    uint4 u[4];
#pragma unroll
    for (int m = 0; m < 4; ++m) {
      int s = esrc[j + 4 * m + q];
      u[m] = *(const uint4*)(Hc + (((uint)s << 8) + off16));
    }
#pragma unroll
    for (int m = 0; m < 4; ++m) {
      acc[0] += blo(u[m].x); acc[1] += bhi(u[m].x);
      acc[2] += blo(u[m].y); acc[3] += bhi(u[m].y);
      acc[4] += blo(u[m].z); acc[5] += bhi(u[m].z);
      acc[6] += blo(u[m].w); acc[7] += bhi(u[m].w);
    }
  }
  for (; j + 4 <= end; j += 4) {
    int s = esrc[j + q];
    uint4 u = *(const uint4*)(Hc + (((uint)s << 8) + off16));
    acc[0] += blo(u.x); acc[1] += bhi(u.x);
    acc[2] += blo(u.y); acc[3] += bhi(u.y);
    acc[4] += blo(u.z); acc[5] += bhi(u.z);
    acc[6] += blo(u.w); acc[7] += bhi(u.w);
  }
  int rem = end - j;  // 0..3
  if (rem) {
    bool p = q < rem;
    int s = p ? esrc[j + q] : node;
    uint4 u = *(const uint4*)(Hc + (((uint)s << 8) + off16));
    if (p) {
      acc[0] += blo(u.x); acc[1] += bhi(u.x);
      acc[2] += blo(u.y); acc[3] += bhi(u.y);
      acc[4] += blo(u.z); acc[5] += bhi(u.z);
      acc[6] += blo(u.w); acc[7] += bhi(u.w);
    }
  }
  // cross-quarter reduce: lanes {l, l+16, l+32, l+48}
#pragma unroll
  for (int k = 0; k < 8; ++k) {
    acc[k] += __shfl_xor(acc[k], 16);
    acc[k] += __shfl_xor(acc[k], 32);
  }
  // this lane's 2 output cols: [8l+2q, 8l+2q+1]
  float s0 = (q & 2) ? ((q & 1) ? acc[6] : acc[4]) : ((q & 1) ? acc[2] : acc[0]);
  float s1 = (q & 2) ? ((q & 1) ? acc[7] : acc[5]) : ((q & 1) ? acc[3] : acc[1]);
  uint us = *(const uint*)(Hc + (((uint)node << 8) + off16 + ((uint)q << 2)));
  float dd = dinv[node];
  float2 bb = *(const float2*)((const char*)b + (off16 << 1) + ((uint)q << 3));
  float ox = fmaxf((s0 + blo(us)) * dd + bb.x, 0.f);
  float oy = fmaxf((s1 + bhi(us)) * dd + bb.y, 0.f);
  float2 o = {ox, oy};
  *(float2*)((char*)out + ((size_t)node << 9) + (off16 << 1) + ((uint)q << 3)) = o;
}

// ---------------- gather 40-wide (128B padded rows): 12 edges in flight ----------------

__launch_bounds__(256)
__global__ void gather40(const int2* __restrict__ rp, const int* __restrict__ esrc,
                         const float* __restrict__ dinv, const uint* __restrict__ H2,
                         const float* __restrict__ b, float* __restrict__ out, int n) {
  int lane = threadIdx.x & 63;
  int node = blockIdx.x * 4 + (threadIdx.x >> 6);
  if (node >= n) return;
  int es = lane / 20;       // 0..2 active, 3 idle
  int c = lane % 20;
  uint c4 = (uint)c << 2;
  bool act = lane < 60;
  const char* Hc = (const char*)H2;
  int2 be = rp[node];
  int j = be.x, end = be.y;
  float ax[4] = {}, ay[4] = {};
  for (; j + 12 <= end; j += 12) {
    uint u[4];
#pragma unroll
    for (int k = 0; k < 4; ++k) {
      int s = act ? esrc[j + 3 * k + es] : node;
      u[k] = *(const uint*)(Hc + (((uint)s << 7) + c4));
    }
    if (act) {
#pragma unroll
      for (int k = 0; k < 4; ++k) { ax[k] += blo(u[k]); ay[k] += bhi(u[k]); }
    }
  }
  if (j + 6 <= end) {
    uint u[2];
#pragma unroll
    for (int k = 0; k < 2; ++k) {
      int s = act ? esrc[j + 3 * k + es] : node;
      u[k] = *(const uint*)(Hc + (((uint)s << 7) + c4));
    }
    if (act) {
#pragma unroll
      for (int k = 0; k < 2; ++k) { ax[k] += blo(u[k]); ay[k] += bhi(u[k]); }
    }
    j += 6;
  }
  int rem = end - j;  // 0..5
  {
    bool pa = act && (es < rem);
    bool pb = act && (3 + es < rem);
    int sa = pa ? esrc[j + es] : node;
    int sb = pb ? esrc[j + 3 + es] : node;
    uint ua = *(const uint*)(Hc + (((uint)sa << 7) + c4));
    uint ub = *(const uint*)(Hc + (((uint)sb << 7) + c4));
    ax[0] += pa ? blo(ua) : 0.f; ay[0] += pa ? bhi(ua) : 0.f;
    ax[1] += pb ? blo(ub) : 0.f; ay[1] += pb ? bhi(ub) : 0.f;
  }
  float gx = (ax[0] + ax[1]) + (ax[2] + ax[3]);
  float gy = (ay[0] + ay[1]) + (ay[2] + ay[3]);
  float tx = gx + __shfl(gx, c + 20) + __shfl(gx, c + 40);
  float ty = gy + __shfl(gy, c + 20) + __shfl(gy, c + 40);
  if (lane < 20) {
    uint us = *(const uint*)(Hc + (((uint)node << 7) + c4));
    float dd = dinv[node];
    float2 bb = ((const float2*)b)[c];
    float2 o = {(tx + blo(us)) * dd + bb.x, (ty + bhi(us)) * dd + bb.y};
    ((float2*)out)[(size_t)node * 20 + c] = o;
  }
}

// ---------------- launch ----------------

extern "C" void kernel_launch(void* const* d_in, const int* in_sizes, int n_in,
                              void* d_out, int out_size, void* d_ws, size_t ws_size,
                              hipStream_t stream) {
  const float* x  = (const float*)d_in[0];
  const int*   ei = (const int*)d_in[1];
  const float* W1 = (const float*)d_in[2];
  const float* b1 = (const float*)d_in[3];
  const float* W2 = (const float*)d_in[4];
  const float* b2 = (const float*)d_in[5];

  int n = in_sizes[0] / 128;   // 100000
  int E = in_sizes[1] / 2;     // 1600000
  const int* src = ei;
  const int* dst = ei + E;

  float* out = (float*)d_out;
  float* logits = out;                    // n*40
  float* hidden = out + (size_t)n * 40;   // n*128

  int nbuck = (n + BUCK_SIZE - 1) >> BUCK_SHIFT;  // 782
  int nchunk = (E + CHUNK - 1) / CHUNK;           // 391
  int ngrow = (n + 127) / 128;                    // 782

  // workspace layout (4-byte units)
  const int PAD = 131072;
  float*  dinv = (float*)d_ws;                          // n
  int2*   rp   = (int2*)((int*)d_ws + PAD);             // n int2 (2*PAD ints)
  int*    bcur = (int*)d_ws + 3 * PAD;                  // 1024
  int*    esrc = (int*)d_ws + 3 * PAD + 1024;           // nbuck<<CAP_SHIFT
  ushort* h1s  = (ushort*)(esrc + ((size_t)nbuck << CAP_SHIFT));  // n*128 bf16
  ushort* h2s  = h1s;                                   // alias h1s (dead after gather128)
  ushort* wt1  = h1s + (size_t)n * 128;                 // 128*128 bf16
  ushort* wt2  = wt1 + 128 * 128;                       // 48*128 bf16
  uint*   pairs = (uint*)h1s;  // aliases h1s: dead before gemm1 writes h1s

  // ---- CSR build (rp, esrc, dinv) + weight prep ----
  binit<<<(nbuck + 255) / 256, 256, 0, stream>>>(bcur, nbuck);
  prep_wt<<<64, 256, 0, stream>>>(W1, W2, wt1, wt2);
  bucket_scatter<<<nchunk, 256, 0, stream>>>(src, dst, bcur, pairs, E, nbuck);
  fine_fill2<<<nbuck, 128, 0, stream>>>(bcur, pairs, esrc, rp, dinv, n, nbuck);

  // ---- layer 1 ----
  gemm1_mfma<<<ngrow, 256, 0, stream>>>(x, wt1, dinv, h1s, n);
  gather128<<<(n + 3) / 4, 256, 0, stream>>>(rp, esrc, dinv, (const uint*)h1s, b1,
                                             hidden, n);

  // ---- layer 2 ----
  gemm2_mfma<<<ngrow, 256, 0, stream>>>(hidden, wt2, dinv, h2s, n);
  gather40<<<(n + 3) / 4, 256, 0, stream>>>(rp, esrc, dinv, (const uint*)h2s, b2,
                                            logits, n);
}